// Round 11
// baseline (493.010 us; speedup 1.0000x reference)
//
#include <hip/hip_runtime.h>
#include <hip/hip_bf16.h>

#define DEV __device__ __forceinline__

typedef __attribute__((ext_vector_type(8))) short bf16x8;
typedef __attribute__((ext_vector_type(4))) float f32x4;
typedef unsigned int u32;
typedef unsigned long long u64;

DEV short f2bf(float f) {
  union { float f; u32 u; } x; x.f = f;
  u32 r = x.u + 0x7fffu + ((x.u >> 16) & 1u);   // RNE
  return (short)(r >> 16);
}

DEV void gload_lds16(const void* g, void* l) {
  __builtin_amdgcn_global_load_lds(
      (const __attribute__((address_space(1))) u32*)g,
      (__attribute__((address_space(3))) u32*)l, 16, 0, 0);
}

// Stage a 128-row x 64-short bf16 tile (row stride 2048 B in global) into LDS,
// linear dest, XOR-pre-swizzled source (rule #21).
DEV void stage_t128(const char* base, int ktb, char* lds, int w, int lane) {
  int r8 = lane >> 3;
  int csw = ((lane & 7) ^ r8) << 4;
#pragma unroll
  for (int i = 0; i < 4; ++i) {
    int c = w * 4 + i;
    gload_lds16(base + (size_t)(c * 8 + r8) * 2048 + ktb + csw, lds + c * 1024);
  }
}

// XOR-swizzled fragment read matching the staging layout. col in shorts.
DEV bf16x8 frag(const short* L, int row, int col) {
  return *(const bf16x8*)&L[row * 64 + (col ^ ((row & 7) << 3))];
}

// ---------- fused prologue: aconv (fp32->bf16), wconv4 (transpose), pack_mask ----------
__global__ __launch_bounds__(256) void prologue(
    const float* __restrict__ q, const float* __restrict__ k, const float* __restrict__ v,
    short* __restrict__ qb, short* __restrict__ kb, short* __restrict__ vb,
    const float* __restrict__ W0, const float* __restrict__ W1,
    const float* __restrict__ W2, const float* __restrict__ W3,
    short* __restrict__ WtAll,
    const int* __restrict__ mask, const int* __restrict__ tmask, u64* __restrict__ pk) {
  int bx = blockIdx.x;
  if (bx < 12288) {                       // ---- activation convert ----
    int z = bx >> 12, bi = bx & 4095;
    const float* src = z == 0 ? q : z == 1 ? k : v;
    short* dst = z == 0 ? qb : z == 1 ? kb : vb;
    size_t i = ((size_t)bi * 256 + threadIdx.x) * 8;
    float4 f0 = *(const float4*)(src + i);
    float4 f1 = *(const float4*)(src + i + 4);
    bf16x8 o;
    o[0] = f2bf(f0.x); o[1] = f2bf(f0.y); o[2] = f2bf(f0.z); o[3] = f2bf(f0.w);
    o[4] = f2bf(f1.x); o[5] = f2bf(f1.y); o[6] = f2bf(f1.z); o[7] = f2bf(f1.w);
    *(bf16x8*)(dst + i) = o;
  } else if (bx < 13312) {                // ---- weight convert+transpose ----
    int idx = bx - 12288;
    int z = idx >> 8, rem = idx & 255;
    const float* W = z == 0 ? W0 : z == 1 ? W1 : z == 2 ? W2 : W3;
    short* Wt = WtAll + (size_t)z * 1024 * 1024;
    __shared__ short tile[64][65];
    int k0 = (rem >> 4) * 64, n0 = (rem & 15) * 64;
    int t = threadIdx.x;
    int r = t >> 2, c = (t & 3) * 16;
    const float* src = W + (size_t)(k0 + r) * 1024 + n0 + c;
#pragma unroll
    for (int i = 0; i < 16; i += 4) {
      float4 f = *(const float4*)(src + i);
      tile[r][c + i + 0] = f2bf(f.x);
      tile[r][c + i + 1] = f2bf(f.y);
      tile[r][c + i + 2] = f2bf(f.z);
      tile[r][c + i + 3] = f2bf(f.w);
    }
    __syncthreads();
    bf16x8 v0, v1;
#pragma unroll
    for (int i = 0; i < 8; ++i) v0[i] = tile[c + i][r];
#pragma unroll
    for (int i = 0; i < 8; ++i) v1[i] = tile[c + 8 + i][r];
    short* dst = Wt + (size_t)(n0 + r) * 1024 + k0 + c;
    *(bf16x8*)(dst) = v0;
    *(bf16x8*)(dst + 8) = v1;
  } else {                                // ---- mask packing ----
    int bn = bx - 13312;                  // (b*1024 + n)
    int b = bn >> 10;
    int t = threadIdx.x, w = t >> 6, lane = t & 63;
    const int* tr = tmask + (size_t)bn * 1024;
    const int* mr = mask + b * 1024;
#pragma unroll
    for (int it = 0; it < 4; ++it) {
      int m = it * 256 + w * 64 + lane;
      bool on = (mr[m] != 0) && (tr[m] != 0);
      u64 bits = __ballot(on);
      if (lane == 0) pk[(size_t)bn * 16 + it * 4 + w] = bits;
    }
  }
}

// ---------- projection GEMMs: z=0 qh, z=1 kh, z=2 vht (= Wv^T @ v^T) ----------
// qh is pre-scaled by 0.125*log2(e) so attention can use exp2 directly.
#define QSCALE 0.18033688011112042f

__global__ __launch_bounds__(256, 2) void gemm_qkv(
    const short* __restrict__ qb, const short* __restrict__ kb, const short* __restrict__ vb,
    const short* __restrict__ WtAll,
    short* __restrict__ qh, short* __restrict__ kh, short* __restrict__ vht) {
  int flat = blockIdx.y * 8 + blockIdx.x;   // 1536 blocks
  int nid = (flat & 7) * 192 + (flat >> 3); // XCD chunking (1536 = 8*192, bijective)
  int zz = nid >> 9;
  int rr = nid & 511;

  const short* A; const short* Bw; float cs = 1.0f;
  int bm, bn;
  if (zz == 0)      { A = qb; Bw = WtAll;                cs = QSCALE;
                      bm = (rr >> 3) * 128; bn = (rr & 7) * 128; }
  else if (zz == 1) { A = kb; Bw = WtAll + 1048576;
                      bm = (rr >> 3) * 128; bn = (rr & 7) * 128; }
  else              { A = WtAll + 2 * 1048576; Bw = vb;   // vht: A=Wvt(1024), B=vb(8192)
                      bm = (rr >> 6) * 128; bn = (rr & 63) * 128; }

  __shared__ __align__(16) short As[128 * 64];
  __shared__ __align__(16) short Bs[128 * 64];

  int tid = threadIdx.x;
  int lane = tid & 63, w = tid >> 6;
  int wm = w >> 1, wn = w & 1;
  int lr = lane & 15, lg = lane >> 4;

  const f32x4 fz = {0.f, 0.f, 0.f, 0.f};
  f32x4 acc[4][4];
#pragma unroll
  for (int i = 0; i < 4; ++i)
#pragma unroll
    for (int j = 0; j < 4; ++j) acc[i][j] = fz;

  const char* abase = (const char*)A + (size_t)bm * 2048;
  const char* bbase = (const char*)Bw + (size_t)bn * 2048;

  for (int ktb = 0; ktb < 2048; ktb += 128) {
    stage_t128(abase, ktb, (char*)As, w, lane);
    stage_t128(bbase, ktb, (char*)Bs, w, lane);
    __syncthreads();
#pragma unroll
    for (int ks = 0; ks < 2; ++ks) {
      bf16x8 af[4], bfr[4];
#pragma unroll
      for (int mi = 0; mi < 4; ++mi)
        af[mi] = frag(As, wm * 64 + mi * 16 + lr, ks * 32 + lg * 8);
#pragma unroll
      for (int ni = 0; ni < 4; ++ni)
        bfr[ni] = frag(Bs, wn * 64 + ni * 16 + lr, ks * 32 + lg * 8);
#pragma unroll
      for (int mi = 0; mi < 4; ++mi)
#pragma unroll
        for (int ni = 0; ni < 4; ++ni)
          acc[mi][ni] = __builtin_amdgcn_mfma_f32_16x16x32_bf16(af[mi], bfr[ni], acc[mi][ni], 0, 0, 0);
    }
    __syncthreads();
  }

  if (zz < 2) {
    short* Ch = (zz == 0) ? qh : kh;
#pragma unroll
    for (int mi = 0; mi < 4; ++mi)
#pragma unroll
      for (int ni = 0; ni < 4; ++ni) {
        int ccol = bn + wn * 64 + ni * 16 + lr;
        int h = ccol >> 6, d = ccol & 63;
#pragma unroll
        for (int j = 0; j < 4; ++j) {
          int r = bm + wm * 64 + mi * 16 + lg * 4 + j;
          int bb = r >> 10, n = r & 1023;
          Ch[(((size_t)bb * 16 + h) * 1024 + n) * 64 + d] = f2bf(acc[mi][ni][j] * cs);
        }
      }
  } else {
    // row r = h*64+dd (Wv output dim), col = b*1024+n -> vht[(b*16+h)*65536 + dd*1024 + n]
#pragma unroll
    for (int mi = 0; mi < 4; ++mi)
#pragma unroll
      for (int ni = 0; ni < 4; ++ni) {
        int ccol = bn + wn * 64 + ni * 16 + lr;
        int bb = ccol >> 10, n = ccol & 1023;
#pragma unroll
        for (int j = 0; j < 4; ++j) {
          int r = bm + wm * 64 + mi * 16 + lg * 4 + j;
          int h = r >> 6, dd = r & 63;
          vht[((size_t)bb * 16 + h) * 65536 + dd * 1024 + n] = f2bf(acc[mi][ni][j]);
        }
      }
  }
}

// ---------- output GEMM: x(8192x1024 bf16) @ Wot^T + bo -> fp32 ----------
__global__ __launch_bounds__(256, 2) void gemm_out(
    const short* __restrict__ X, const short* __restrict__ Wot,
    const float* __restrict__ bo, float* __restrict__ out) {
  int flat = blockIdx.y * 8 + blockIdx.x;       // grid (8, 64)
  int nid = (flat & 7) * 64 + (flat >> 3);
  int bm = (nid >> 3) * 128, bn = (nid & 7) * 128;

  __shared__ __align__(16) short As[128 * 64];
  __shared__ __align__(16) short Bs[128 * 64];
  int tid = threadIdx.x, lane = tid & 63, w = tid >> 6;
  int wm = w >> 1, wn = w & 1, lr = lane & 15, lg = lane >> 4;

  const f32x4 fz = {0.f, 0.f, 0.f, 0.f};
  f32x4 acc[4][4];
#pragma unroll
  for (int i = 0; i < 4; ++i)
#pragma unroll
    for (int j = 0; j < 4; ++j) acc[i][j] = fz;

  const char* abase = (const char*)X + (size_t)bm * 2048;
  const char* bbase = (const char*)Wot + (size_t)bn * 2048;

  for (int ktb = 0; ktb < 2048; ktb += 128) {
    stage_t128(abase, ktb, (char*)As, w, lane);
    stage_t128(bbase, ktb, (char*)Bs, w, lane);
    __syncthreads();
#pragma unroll
    for (int ks = 0; ks < 2; ++ks) {
      bf16x8 af[4], bfr[4];
#pragma unroll
      for (int mi = 0; mi < 4; ++mi)
        af[mi] = frag(As, wm * 64 + mi * 16 + lr, ks * 32 + lg * 8);
#pragma unroll
      for (int ni = 0; ni < 4; ++ni)
        bfr[ni] = frag(Bs, wn * 64 + ni * 16 + lr, ks * 32 + lg * 8);
#pragma unroll
      for (int mi = 0; mi < 4; ++mi)
#pragma unroll
        for (int ni = 0; ni < 4; ++ni)
          acc[mi][ni] = __builtin_amdgcn_mfma_f32_16x16x32_bf16(af[mi], bfr[ni], acc[mi][ni], 0, 0, 0);
    }
    __syncthreads();
  }
#pragma unroll
  for (int mi = 0; mi < 4; ++mi)
#pragma unroll
    for (int ni = 0; ni < 4; ++ni) {
      int ccol = bn + wn * 64 + ni * 16 + lr;
      float bias = bo[ccol];
#pragma unroll
      for (int j = 0; j < 4; ++j) {
        int r = bm + wm * 64 + mi * 16 + lg * 4 + j;
        out[(size_t)r * 1024 + ccol] = acc[mi][ni][j] + bias;
      }
    }
}

// ---------- flash attention: 8 waves, 256 q-rows per block ----------
DEV void stage_kv8(const char* kbase, const char* vbase, int kv0,
                   short* Ksb, short* Vsb, int w, int lane) {
  int row = lane >> 3;
  int colb = ((lane & 7) ^ row) << 4;            // pre-swizzled source column
  gload_lds16(kbase + (size_t)(kv0 + w * 8 + row) * 128 + colb, (char*)Ksb + w * 1024);
  gload_lds16(vbase + (size_t)(w * 8 + row) * 2048 + kv0 * 2 + colb, (char*)Vsb + w * 1024);
}

__global__ __launch_bounds__(512, 4) void attn(
    const short* __restrict__ qh, const short* __restrict__ kh, const short* __restrict__ vht,
    const u64* __restrict__ pk, short* __restrict__ x) {
  __shared__ __align__(16) short Ks[2][4096];   // [key][d], XOR-swizzled
  __shared__ __align__(16) short Vs[2][4096];   // [d][key], XOR-swizzled
  __shared__ __align__(16) short Ps[256 * 64];  // [qrow][key], XOR-swizzled, wave-private rows

  int flat = blockIdx.y * 8 + blockIdx.x;       // grid (8, 64) = 512 blocks
  int nid = (flat & 7) * 64 + (flat >> 3);      // XCD chunking (bijective: 512 = 8*64)
  int bh = nid >> 2, qp = nid & 3;              // 4 q-pairs (256 rows) per head
  int b = bh >> 4;
  int tid = threadIdx.x, lane = tid & 63, w = tid >> 6;   // 8 waves
  int lr = lane & 15, lg = lane >> 4;

  // Q fragments: wave w owns rows qp*256 + w*32 .. +32
  bf16x8 qa[2][2];
  {
    const short* qb2 = qh + ((size_t)bh * 1024 + qp * 256 + w * 32) * 64;
#pragma unroll
    for (int mi = 0; mi < 2; ++mi)
#pragma unroll
      for (int ks = 0; ks < 2; ++ks)
        qa[mi][ks] = *(const bf16x8*)(qb2 + (mi * 16 + lr) * 64 + ks * 32 + lg * 8);
  }

  const f32x4 fz = {0.f, 0.f, 0.f, 0.f};
  f32x4 o[2][4];
  float psum[2][4];
#pragma unroll
  for (int mi = 0; mi < 2; ++mi)
#pragma unroll
    for (int j = 0; j < 4; ++j) { psum[mi][j] = 0.f; o[mi][j] = fz; }

  const char* kbase = (const char*)(kh + (size_t)bh * 65536);
  const char* vbase = (const char*)(vht + (size_t)bh * 65536);
  const u64* pkb = pk + ((size_t)b * 1024 + qp * 256) * 16;

  stage_kv8(kbase, vbase, 0, Ks[0], Vs[0], w, lane);
  __syncthreads();
  int cur = 0;

  for (int t = 0; t < 16; ++t) {
    if (t < 15) stage_kv8(kbase, vbase, (t + 1) * 64, Ks[cur ^ 1], Vs[cur ^ 1], w, lane);

    // packed mask words (L2-resident broadcast loads)
    u64 pw[2][4];
#pragma unroll
    for (int mi = 0; mi < 2; ++mi)
#pragma unroll
      for (int j = 0; j < 4; ++j)
        pw[mi][j] = pkb[(w * 32 + mi * 16 + lg * 4 + j) * 16 + t];

    // S = Q K^T  (qh pre-scaled by 0.125*log2e)
    f32x4 s[2][4];
#pragma unroll
    for (int mi = 0; mi < 2; ++mi)
#pragma unroll
      for (int ni = 0; ni < 4; ++ni) s[mi][ni] = fz;
    __builtin_amdgcn_s_setprio(1);
#pragma unroll
    for (int ks = 0; ks < 2; ++ks) {
      bf16x8 kb2[4];
#pragma unroll
      for (int ni = 0; ni < 4; ++ni)
        kb2[ni] = *(const bf16x8*)&Ks[cur][(ni * 16 + lr) * 64 + ((ks * 32 + lg * 8) ^ ((lr & 7) << 3))];
#pragma unroll
      for (int mi = 0; mi < 2; ++mi)
#pragma unroll
        for (int ni = 0; ni < 4; ++ni)
          s[mi][ni] = __builtin_amdgcn_mfma_f32_16x16x32_bf16(qa[mi][ks], kb2[ni], s[mi][ni], 0, 0, 0);
    }
    __builtin_amdgcn_s_setprio(0);

    // P = mask ? exp2(S) : 0 ; psum accumulate; P -> LDS (bf16, 2-op round)
#pragma unroll
    for (int mi = 0; mi < 2; ++mi)
#pragma unroll
      for (int j = 0; j < 4; ++j) {
        u32 lo = (u32)pw[mi][j], hi = (u32)(pw[mi][j] >> 32);
        int r = w * 32 + mi * 16 + lg * 4 + j;
        int sw = (r & 7) << 3;
        float rs = 0.f;
#pragma unroll
        for (int ni = 0; ni < 4; ++ni) {
          u32 bit = ((ni < 2 ? lo : hi) >> ((ni & 1) * 16 + lr)) & 1u;
          float e = __builtin_amdgcn_exp2f(s[mi][ni][j]);
          float p = bit ? e : 0.f;
          rs += p;
          union { float f; u32 u; } cv; cv.f = p;
          Ps[r * 64 + ((ni * 16 + lr) ^ sw)] = (short)((cv.u + 0x8000u) >> 16);
        }
        psum[mi][j] += rs;
      }

    // O += P V  (P rows are wave-private; no barrier needed around Ps)
    __builtin_amdgcn_s_setprio(1);
#pragma unroll
    for (int ks = 0; ks < 2; ++ks) {
      bf16x8 pa[2], vb2[4];
#pragma unroll
      for (int mi = 0; mi < 2; ++mi)
        pa[mi] = *(const bf16x8*)&Ps[(w * 32 + mi * 16 + lr) * 64 + ((ks * 32 + lg * 8) ^ ((lr & 7) << 3))];
#pragma unroll
      for (int nd = 0; nd < 4; ++nd)
        vb2[nd] = *(const bf16x8*)&Vs[cur][(nd * 16 + lr) * 64 + ((ks * 32 + lg * 8) ^ ((lr & 7) << 3))];
#pragma unroll
      for (int mi = 0; mi < 2; ++mi)
#pragma unroll
        for (int nd = 0; nd < 4; ++nd)
          o[mi][nd] = __builtin_amdgcn_mfma_f32_16x16x32_bf16(pa[mi], vb2[nd], o[mi][nd], 0, 0, 0);
    }
    __builtin_amdgcn_s_setprio(0);
    __syncthreads();
    cur ^= 1;
  }

  // epilogue: sum-reduce across 16-lane groups, normalize, store
  short* xb = x + ((size_t)b * 1024) * 1024 + (bh & 15) * 64;
#pragma unroll
  for (int mi = 0; mi < 2; ++mi)
#pragma unroll
    for (int j = 0; j < 4; ++j) {
      float rs = psum[mi][j];
#pragma unroll
      for (int dd = 1; dd < 16; dd <<= 1) rs += __shfl_xor(rs, dd, 64);
      float inv = rs > 0.f ? 1.0f / rs : 0.f;
      int qg = qp * 256 + w * 32 + mi * 16 + lg * 4 + j;
#pragma unroll
      for (int nd = 0; nd < 4; ++nd) {
        int d = nd * 16 + lr;
        xb[(size_t)qg * 1024 + d] = f2bf(o[mi][nd][j] * inv);
      }
    }
}

extern "C" void kernel_launch(void* const* d_in, const int* in_sizes, int n_in,
                              void* d_out, int out_size, void* d_ws, size_t ws_size,
                              hipStream_t stream) {
  const float* q = (const float*)d_in[0];
  const float* k = (const float*)d_in[1];
  const float* v = (const float*)d_in[2];
  const int* mask = (const int*)d_in[3];
  const int* tmask = (const int*)d_in[4];
  const float* Wq = (const float*)d_in[5];
  const float* Wk = (const float*)d_in[6];
  const float* Wv = (const float*)d_in[7];
  const float* Wo = (const float*)d_in[8];
  const float* bo = (const float*)d_in[9];
  float* out = (float*)d_out;

  char* ws = (char*)d_ws;
  const size_t MB = 1u << 20;
  if (ws_size < 73 * MB) return;
  short* WtAll = (short*)(ws + 0 * MB);   // Wqt,Wkt,Wvt,Wot contiguous (8 MB)
  short* qh  = (short*)(ws + 8 * MB);
  short* kh  = (short*)(ws + 24 * MB);
  short* vb  = (short*)(ws + 40 * MB);    // v in bf16 (B-operand of the vht GEMM)
  short* vht = (short*)(ws + 56 * MB);
  u64*   pkb = (u64*)(ws + 72 * MB);      // 1 MB packed masks
  short* x   = (short*)(ws + 40 * MB);    // aliases vb (dead after gemm_qkv)
  // qb/kb live in d_out (32 MB, overwritten by gemm_out at the very end).
  short* qbA = (short*)d_out;
  short* kbA = (short*)d_out + 8 * 1024 * 1024;

  prologue<<<dim3(21504), 256, 0, stream>>>(q, k, v, qbA, kbA, vb,
                                            Wq, Wk, Wv, Wo, WtAll,
                                            mask, tmask, pkb);
  gemm_qkv<<<dim3(8, 192), 256, 0, stream>>>(qbA, kbA, vb, WtAll, qh, kh, vht);
  attn<<<dim3(8, 64), 512, 0, stream>>>(qh, kh, vht, pkb, x);
  gemm_out<<<dim3(8, 64), 256, 0, stream>>>(x, WtAll + 3 * 1024 * 1024, bo, out);
}